// Round 3
// baseline (313.125 us; speedup 1.0000x reference)
//
#include <hip/hip_runtime.h>
#include <hip/hip_bf16.h>

// ---------------- types ----------------
typedef __bf16 bf16;
typedef __attribute__((ext_vector_type(8))) __bf16 bf16x8;
typedef __attribute__((ext_vector_type(4))) float f32x4;
typedef unsigned int u32;
typedef const __attribute__((address_space(1))) u32* gptr_t;
typedef __attribute__((address_space(3))) u32* lptr_t;

#define N_EMB 1024
#define N_HEAD 16
#define HEAD_DIM 64
#define T_SEQ 2048
#define BATCH 2
#define M_TOT (BATCH * T_SEQ)   // 4096
#define N_QKV (3 * N_EMB)       // 3072
#define KDIM 1024

// round-to-nearest-even f32 -> bf16
__device__ inline unsigned short f2bu(float f) {
    unsigned u = __builtin_bit_cast(unsigned, f);
    return (unsigned short)((u + 0x7fffu + ((u >> 16) & 1u)) >> 16);
}
__device__ inline bf16 f2b(float f) {
    unsigned short s = f2bu(f);
    return __builtin_bit_cast(bf16, s);
}

// ---------------- cast x (f32 -> bf16), 4 elems/thread ----------------
__global__ __launch_bounds__(256) void k_cast(const float* __restrict__ x,
                                              bf16* __restrict__ xb, int n4) {
    int i = blockIdx.x * 256 + threadIdx.x;
    if (i < n4) {
        float4 v = reinterpret_cast<const float4*>(x)[i];
        ushort4 u;
        u.x = f2bu(v.x); u.y = f2bu(v.y); u.z = f2bu(v.z); u.w = f2bu(v.w);
        reinterpret_cast<ushort4*>(xb)[i] = u;
    }
}

// ---------------- transpose + cast: W [K][N] f32 -> Wt [N][K] bf16 ----------------
__global__ __launch_bounds__(256) void k_transpose(const float* __restrict__ W,
                                                   bf16* __restrict__ Wt,
                                                   int K, int N) {
    __shared__ float tile[32][33];
    int k0 = blockIdx.x * 32;
    int n0 = blockIdx.y * 32;
    int tx = threadIdx.x & 31;
    int ty = threadIdx.x >> 5;   // 0..7
    for (int j = 0; j < 32; j += 8)
        tile[ty + j][tx] = W[(k0 + ty + j) * N + n0 + tx];
    __syncthreads();
    for (int j = 0; j < 32; j += 8)
        Wt[(n0 + ty + j) * (long)K + k0 + tx] = f2b(tile[tx][ty + j]);
}

// =====================================================================
// m97-structure GEMM main loop (unchanged from R2)
// =====================================================================
#define GEMM_MAINLOOP(A_, Bt_, m0_, n0_)                                          \
    __shared__ __align__(16) bf16 As[128 * 32];                                   \
    __shared__ __align__(16) bf16 Bs[128 * 32];                                   \
    const int lane = threadIdx.x & 63;                                            \
    const int w    = threadIdx.x >> 6;                                            \
    const int wr   = w >> 1;                                                      \
    const int wc   = w & 1;                                                       \
    const int r    = lane & 15;                                                   \
    const int ko   = (lane >> 4) * 8;                                             \
    const int srow = w * 32 + (lane >> 2);                                        \
    const int sk   = (lane & 3) * 8;                                              \
    const bf16* a_g0 = A_ + (size_t)(m0_ + srow) * KDIM + sk;                     \
    const bf16* a_g1 = a_g0 + 16 * KDIM;                                          \
    const bf16* b_g0 = Bt_ + (size_t)(n0_ + srow) * KDIM + sk;                    \
    const bf16* b_g1 = b_g0 + 16 * KDIM;                                          \
    bf16* a_l0 = As + (w * 2) * 512;                                              \
    bf16* a_l1 = As + (w * 2 + 1) * 512;                                          \
    bf16* b_l0 = Bs + (w * 2) * 512;                                              \
    bf16* b_l1 = Bs + (w * 2 + 1) * 512;                                          \
    f32x4 acc[4][4];                                                              \
    for (int i = 0; i < 4; ++i)                                                   \
        for (int j = 0; j < 4; ++j) acc[i][j] = (f32x4){0.f, 0.f, 0.f, 0.f};      \
    for (int k0 = 0; k0 < KDIM; k0 += 32) {                                       \
        __builtin_amdgcn_global_load_lds((gptr_t)(const void*)(a_g0 + k0),        \
                                         (lptr_t)(void*)a_l0, 16, 0, 0);          \
        __builtin_amdgcn_global_load_lds((gptr_t)(const void*)(a_g1 + k0),        \
                                         (lptr_t)(void*)a_l1, 16, 0, 0);          \
        __builtin_amdgcn_global_load_lds((gptr_t)(const void*)(b_g0 + k0),        \
                                         (lptr_t)(void*)b_l0, 16, 0, 0);          \
        __builtin_amdgcn_global_load_lds((gptr_t)(const void*)(b_g1 + k0),        \
                                         (lptr_t)(void*)b_l1, 16, 0, 0);          \
        __syncthreads();                                                          \
        bf16x8 af[4], bfr[4];                                                     \
        for (int m = 0; m < 4; ++m)                                               \
            af[m] = *reinterpret_cast<const bf16x8*>(As + (wr * 64 + m * 16 + r) * 32 + ko); \
        for (int n = 0; n < 4; ++n)                                               \
            bfr[n] = *reinterpret_cast<const bf16x8*>(Bs + (wc * 64 + n * 16 + r) * 32 + ko); \
        for (int m = 0; m < 4; ++m)                                               \
            for (int n = 0; n < 4; ++n)                                           \
                acc[m][n] = __builtin_amdgcn_mfma_f32_16x16x32_bf16(af[m], bfr[n], acc[m][n], 0, 0, 0); \
        __syncthreads();                                                          \
    }

// ---------------- QKV GEMM -> q/k [B,H,T,64], V TRANSPOSED [B,H,64,T] ----------------
__global__ __launch_bounds__(256) void k_gemm_qkv(const bf16* __restrict__ A,
                                                  const bf16* __restrict__ Bt,
                                                  const float* __restrict__ bias,
                                                  bf16* __restrict__ qb,
                                                  bf16* __restrict__ kb,
                                                  bf16* __restrict__ vb) {
    const int m0 = blockIdx.x * 128;
    const int n0 = blockIdx.y * 128;
    GEMM_MAINLOOP(A, Bt, m0, n0)
    const int col   = lane & 15;
    const int rbase = (lane >> 4) * 4;
    for (int nn = 0; nn < 4; ++nn) {
        int n = n0 + wc * 64 + nn * 16 + col;
        float bv = bias[n];
        int which = n >> 10;     // 0:q 1:k 2:v (uniform across the 16 lanes of a group)
        int c  = n & 1023;
        int h  = c >> 6;
        int dh = c & 63;
        if (which == 2) {
            // V transposed: [B,H,64,T], pack 4 consecutive t per lane -> 8B store
            for (int mm = 0; mm < 4; ++mm) {
                int m = m0 + wr * 64 + mm * 16 + rbase;
                int b_ = m >> 11;
                int t  = m & 2047;
                ushort4 u;
                u.x = f2bu(acc[mm][nn][0] + bv);
                u.y = f2bu(acc[mm][nn][1] + bv);
                u.z = f2bu(acc[mm][nn][2] + bv);
                u.w = f2bu(acc[mm][nn][3] + bv);
                *reinterpret_cast<ushort4*>(
                    vb + ((size_t)(b_ * N_HEAD + h) * HEAD_DIM + dh) * T_SEQ + t) = u;
            }
        } else {
            bf16* dst = (which == 0) ? qb : kb;
            for (int mm = 0; mm < 4; ++mm) {
                for (int i = 0; i < 4; ++i) {
                    int m = m0 + wr * 64 + mm * 16 + rbase + i;
                    int b_ = m >> 11;
                    int t  = m & 2047;
                    dst[(((b_ * N_HEAD + h) * T_SEQ) + t) * HEAD_DIM + dh] =
                        f2b(acc[mm][nn][i] + bv);
                }
            }
        }
    }
}

// ---------------- proj GEMM: y[4096x1024] @ Wp[1024x1024] + bias -> out f32
__global__ __launch_bounds__(256) void k_gemm_proj(const bf16* __restrict__ A,
                                                   const bf16* __restrict__ Bt,
                                                   const float* __restrict__ bias,
                                                   float* __restrict__ out) {
    const int m0 = blockIdx.x * 128;
    const int n0 = blockIdx.y * 128;
    GEMM_MAINLOOP(A, Bt, m0, n0)
    const int col   = lane & 15;
    const int rbase = (lane >> 4) * 4;
    for (int nn = 0; nn < 4; ++nn) {
        int n = n0 + wc * 64 + nn * 16 + col;
        float bv = bias[n];
        for (int mm = 0; mm < 4; ++mm) {
            for (int i = 0; i < 4; ++i) {
                int m = m0 + wr * 64 + mm * 16 + rbase + i;
                out[(size_t)m * N_EMB + n] = acc[mm][nn][i] + bv;
            }
        }
    }
}

// ---------------- flash attention (causal), one wave = 16 q rows ----------------
// V is [B,H,64,T] (transposed) -> PV B-fragment is a contiguous 16B load.
__global__ __launch_bounds__(256) void k_attn(const bf16* __restrict__ qb,
                                              const bf16* __restrict__ kb,
                                              const bf16* __restrict__ vb,
                                              bf16* __restrict__ yb) {
    const int lane = threadIdx.x & 63;
    const int w    = threadIdx.x >> 6;
    const int bh   = blockIdx.y;            // 0..31
    const int b    = bh >> 4;
    const int h    = bh & 15;
    // heavy-first: high q-blocks (most k-tiles) dispatch first
    const int qblk = gridDim.x - 1 - blockIdx.x;
    const int q0   = qblk * 64 + w * 16;

    const bf16* Q  = qb + (long)bh * T_SEQ * HEAD_DIM;
    const bf16* K  = kb + (long)bh * T_SEQ * HEAD_DIM;
    const bf16* Vt = vb + (long)bh * HEAD_DIM * T_SEQ;   // [64][T]

    const int r  = lane & 15;
    const int ko = (lane >> 4) * 8;

    bf16x8 q_lo = *reinterpret_cast<const bf16x8*>(Q + (q0 + r) * HEAD_DIM + ko);
    bf16x8 q_hi = *reinterpret_cast<const bf16x8*>(Q + (q0 + r) * HEAD_DIM + 32 + ko);

    f32x4 zero = {0.f, 0.f, 0.f, 0.f};
    f32x4 o[4] = {zero, zero, zero, zero};
    float m_i[4], l_i[4];
    for (int i = 0; i < 4; ++i) { m_i[i] = -3.0e38f; l_i[i] = 0.f; }

    const int rbase = (lane >> 4) * 4;
    const int col   = lane & 15;

    // padded to 40 (80B rows): keeps 16B alignment, breaks row*4 bank aliasing
    __shared__ __align__(16) bf16 p_lds[4][16][40];
    bf16 (*pl)[40] = p_lds[w];

    const int nt = (q0 + 15) / 32 + 1;
    const float scale = 0.125f;

    for (int kt = 0; kt < nt; ++kt) {
        const int kbase = kt * 32;
        // ---- S = Q K^T ----
        f32x4 s[2];
        for (int g = 0; g < 2; ++g) {
            const bf16* kp = K + (kbase + g * 16 + r) * HEAD_DIM + ko;
            bf16x8 k_lo = *reinterpret_cast<const bf16x8*>(kp);
            bf16x8 k_hi = *reinterpret_cast<const bf16x8*>(kp + 32);
            f32x4 t = zero;
            t = __builtin_amdgcn_mfma_f32_16x16x32_bf16(q_lo, k_lo, t, 0, 0, 0);
            t = __builtin_amdgcn_mfma_f32_16x16x32_bf16(q_hi, k_hi, t, 0, 0, 0);
            s[g] = t;
        }
        // ---- mask + scale, row-max ----
        float mt[4];
        for (int i = 0; i < 4; ++i) {
            int qr = q0 + rbase + i;
            float s0 = s[0][i] * scale;
            float s1 = s[1][i] * scale;
            s0 = (kbase + col)      <= qr ? s0 : -3.0e38f;
            s1 = (kbase + 16 + col) <= qr ? s1 : -3.0e38f;
            s[0][i] = s0; s[1][i] = s1;
            mt[i] = fmaxf(s0, s1);
        }
        for (int msk = 1; msk <= 8; msk <<= 1)
            for (int i = 0; i < 4; ++i)
                mt[i] = fmaxf(mt[i], __shfl_xor(mt[i], msk, 64));
        // ---- online softmax ----
        float alpha[4], rs[4];
        for (int i = 0; i < 4; ++i) {
            float mn = fmaxf(m_i[i], mt[i]);
            alpha[i] = expf(m_i[i] - mn);
            m_i[i] = mn;
            float p0 = expf(s[0][i] - mn);   // masked entries underflow to 0
            float p1 = expf(s[1][i] - mn);
            s[0][i] = p0; s[1][i] = p1;
            rs[i] = p0 + p1;
        }
        for (int msk = 1; msk <= 8; msk <<= 1)
            for (int i = 0; i < 4; ++i)
                rs[i] += __shfl_xor(rs[i], msk, 64);
        for (int i = 0; i < 4; ++i)
            l_i[i] = l_i[i] * alpha[i] + rs[i];
        for (int dg = 0; dg < 4; ++dg)
            for (int i = 0; i < 4; ++i)
                o[dg][i] *= alpha[i];
        // ---- P: C-layout -> LDS -> A-layout ----
        for (int g = 0; g < 2; ++g)
            for (int i = 0; i < 4; ++i)
                pl[rbase + i][g * 16 + col] = f2b(s[g][i]);
        asm volatile("s_waitcnt lgkmcnt(0)" ::: "memory");
        bf16x8 pa = *reinterpret_cast<const bf16x8*>(&pl[r][ko]);
        // ---- O += P V  (V^T: contiguous 16B B-fragments) ----
        for (int dg = 0; dg < 4; ++dg) {
            bf16x8 vf = *reinterpret_cast<const bf16x8*>(
                Vt + (size_t)(dg * 16 + r) * T_SEQ + kbase + ko);
            o[dg] = __builtin_amdgcn_mfma_f32_16x16x32_bf16(pa, vf, o[dg], 0, 0, 0);
        }
    }
    // ---- epilogue ----
    for (int i = 0; i < 4; ++i) {
        int t = q0 + rbase + i;
        float inv = 1.f / l_i[i];
        for (int dg = 0; dg < 4; ++dg) {
            int c = h * HEAD_DIM + dg * 16 + col;
            yb[((long)(b * T_SEQ + t)) * N_EMB + c] = f2b(o[dg][i] * inv);
        }
    }
}

extern "C" void kernel_launch(void* const* d_in, const int* in_sizes, int n_in,
                              void* d_out, int out_size, void* d_ws, size_t ws_size,
                              hipStream_t stream) {
    const float* x      = (const float*)d_in[0];
    const float* W_attn = (const float*)d_in[1];
    const float* b_attn = (const float*)d_in[2];
    const float* W_proj = (const float*)d_in[3];
    const float* b_proj = (const float*)d_in[4];
    float* out = (float*)d_out;

    const size_t sz_x   = (size_t)M_TOT * N_EMB;
    const size_t sz_wat = (size_t)N_QKV * N_EMB;
    const size_t sz_wpt = (size_t)N_EMB * N_EMB;
    const size_t sz_hd  = (size_t)BATCH * N_HEAD * T_SEQ * HEAD_DIM;
    const size_t need = (sz_x + sz_wat + sz_wpt + 3 * sz_hd + sz_x) * sizeof(bf16);
    if (ws_size < need) return;

    bf16* xb  = (bf16*)d_ws;
    bf16* wat = xb + sz_x;
    bf16* wpt = wat + sz_wat;
    bf16* qb  = wpt + sz_wpt;
    bf16* kbf = qb + sz_hd;
    bf16* vbf = kbf + sz_hd;   // transposed [B,H,64,T]
    bf16* yb  = vbf + sz_hd;

    k_cast<<<dim3((sz_x / 4 + 255) / 256), 256, 0, stream>>>(x, xb, (int)(sz_x / 4));
    k_transpose<<<dim3(N_EMB / 32, N_QKV / 32), 256, 0, stream>>>(W_attn, wat, N_EMB, N_QKV);
    k_transpose<<<dim3(N_EMB / 32, N_EMB / 32), 256, 0, stream>>>(W_proj, wpt, N_EMB, N_EMB);
    k_gemm_qkv<<<dim3(M_TOT / 128, N_QKV / 128), 256, 0, stream>>>(xb, wat, b_attn, qb, kbf, vbf);
    k_attn<<<dim3(T_SEQ / 64, BATCH * N_HEAD), 256, 0, stream>>>(qb, kbf, vbf, yb);
    k_gemm_proj<<<dim3(M_TOT / 128, N_EMB / 128), 256, 0, stream>>>(yb, wpt, b_proj, out);
}

// Round 4
// 156.379 us; speedup vs baseline: 2.0024x; 2.0024x over previous
//
#include <hip/hip_runtime.h>
#include <hip/hip_bf16.h>

// ---------------- types ----------------
typedef __bf16 bf16;
typedef __attribute__((ext_vector_type(2))) __bf16 bf16x2;
typedef __attribute__((ext_vector_type(4))) __bf16 bf16x4;
typedef __attribute__((ext_vector_type(8))) __bf16 bf16x8;
typedef __attribute__((ext_vector_type(4))) float f32x4;
typedef __attribute__((ext_vector_type(16))) float f32x16;
typedef unsigned int u32;
typedef __attribute__((ext_vector_type(4))) u32 u32x4;
typedef const __attribute__((address_space(1))) u32* gptr_t;
typedef __attribute__((address_space(3))) u32* lptr_t;

#define N_EMB 1024
#define N_HEAD 16
#define HEAD_DIM 64
#define T_SEQ 2048
#define BATCH 2
#define M_TOT (BATCH * T_SEQ)   // 4096
#define N_QKV (3 * N_EMB)       // 3072
#define KDIM 1024

// round-to-nearest-even f32 -> bf16
__device__ inline unsigned short f2bu(float f) {
    unsigned u = __builtin_bit_cast(unsigned, f);
    return (unsigned short)((u + 0x7fffu + ((u >> 16) & 1u)) >> 16);
}
__device__ inline bf16 f2b(float f) {
    unsigned short s = f2bu(f);
    return __builtin_bit_cast(bf16, s);
}
__device__ inline u32 pkbf(float lo, float hi) {
    bf16x2 t; t[0] = (bf16)lo; t[1] = (bf16)hi;
    return __builtin_bit_cast(u32, t);
}

// ---------------- cast x (f32 -> bf16), 4 elems/thread ----------------
__global__ __launch_bounds__(256) void k_cast(const float* __restrict__ x,
                                              bf16* __restrict__ xb, int n4) {
    int i = blockIdx.x * 256 + threadIdx.x;
    if (i < n4) {
        float4 v = reinterpret_cast<const float4*>(x)[i];
        ushort4 u;
        u.x = f2bu(v.x); u.y = f2bu(v.y); u.z = f2bu(v.z); u.w = f2bu(v.w);
        reinterpret_cast<ushort4*>(xb)[i] = u;
    }
}

// ---------------- transpose + cast: W [K][N] f32 -> Wt [N][K] bf16 ----------------
__global__ __launch_bounds__(256) void k_transpose(const float* __restrict__ W,
                                                   bf16* __restrict__ Wt,
                                                   int K, int N) {
    __shared__ float tile[32][33];
    int k0 = blockIdx.x * 32;
    int n0 = blockIdx.y * 32;
    int tx = threadIdx.x & 31;
    int ty = threadIdx.x >> 5;   // 0..7
    for (int j = 0; j < 32; j += 8)
        tile[ty + j][tx] = W[(k0 + ty + j) * N + n0 + tx];
    __syncthreads();
    for (int j = 0; j < 32; j += 8)
        Wt[(n0 + ty + j) * (long)K + k0 + tx] = f2b(tile[tx][ty + j]);
}

// ---------------- V transpose: [B,H,T,64] -> [B,H,64,T] via LDS tile ----------------
__global__ __launch_bounds__(256) void k_vtrans(const bf16* __restrict__ v,
                                                bf16* __restrict__ vt) {
    __shared__ bf16 tile[64 * 76];   // pad 76 halfwords (152B rows, 8B-aligned)
    const int bh = blockIdx.y;
    const int t0 = blockIdx.x * 64;
    const bf16* src = v + (size_t)bh * T_SEQ * HEAD_DIM;
    bf16* dst = vt + (size_t)bh * HEAD_DIM * T_SEQ;
    const int tid = threadIdx.x;
    #pragma unroll
    for (int it = 0; it < 2; ++it) {
        const int row = (tid >> 3) + it * 32;
        const int col = (tid & 7) * 8;
        bf16x8 val = *reinterpret_cast<const bf16x8*>(src + (size_t)(t0 + row) * HEAD_DIM + col);
        bf16x4 lo;  lo[0] = val[0]; lo[1] = val[1]; lo[2] = val[2]; lo[3] = val[3];
        bf16x4 hiv; hiv[0] = val[4]; hiv[1] = val[5]; hiv[2] = val[6]; hiv[3] = val[7];
        *reinterpret_cast<bf16x4*>(&tile[row * 76 + col]) = lo;
        *reinterpret_cast<bf16x4*>(&tile[row * 76 + col + 4]) = hiv;
    }
    __syncthreads();
    #pragma unroll
    for (int it = 0; it < 2; ++it) {
        const int d  = (tid >> 3) + it * 32;
        const int tt = (tid & 7) * 8;
        bf16x8 val;
        #pragma unroll
        for (int q = 0; q < 8; ++q)
            val[q] = tile[(tt + q) * 76 + d];
        *reinterpret_cast<bf16x8*>(dst + (size_t)d * T_SEQ + t0 + tt) = val;
    }
}

// =====================================================================
// m97-structure GEMM main loop (unchanged)
// =====================================================================
#define GEMM_MAINLOOP(A_, Bt_, m0_, n0_)                                          \
    __shared__ __align__(16) bf16 As[128 * 32];                                   \
    __shared__ __align__(16) bf16 Bs[128 * 32];                                   \
    const int lane = threadIdx.x & 63;                                            \
    const int w    = threadIdx.x >> 6;                                            \
    const int wr   = w >> 1;                                                      \
    const int wc   = w & 1;                                                       \
    const int r    = lane & 15;                                                   \
    const int ko   = (lane >> 4) * 8;                                             \
    const int srow = w * 32 + (lane >> 2);                                        \
    const int sk   = (lane & 3) * 8;                                              \
    const bf16* a_g0 = A_ + (size_t)(m0_ + srow) * KDIM + sk;                     \
    const bf16* a_g1 = a_g0 + 16 * KDIM;                                          \
    const bf16* b_g0 = Bt_ + (size_t)(n0_ + srow) * KDIM + sk;                    \
    const bf16* b_g1 = b_g0 + 16 * KDIM;                                          \
    bf16* a_l0 = As + (w * 2) * 512;                                              \
    bf16* a_l1 = As + (w * 2 + 1) * 512;                                          \
    bf16* b_l0 = Bs + (w * 2) * 512;                                              \
    bf16* b_l1 = Bs + (w * 2 + 1) * 512;                                          \
    f32x4 acc[4][4];                                                              \
    for (int i = 0; i < 4; ++i)                                                   \
        for (int j = 0; j < 4; ++j) acc[i][j] = (f32x4){0.f, 0.f, 0.f, 0.f};      \
    for (int k0 = 0; k0 < KDIM; k0 += 32) {                                       \
        __builtin_amdgcn_global_load_lds((gptr_t)(const void*)(a_g0 + k0),        \
                                         (lptr_t)(void*)a_l0, 16, 0, 0);          \
        __builtin_amdgcn_global_load_lds((gptr_t)(const void*)(a_g1 + k0),        \
                                         (lptr_t)(void*)a_l1, 16, 0, 0);          \
        __builtin_amdgcn_global_load_lds((gptr_t)(const void*)(b_g0 + k0),        \
                                         (lptr_t)(void*)b_l0, 16, 0, 0);          \
        __builtin_amdgcn_global_load_lds((gptr_t)(const void*)(b_g1 + k0),        \
                                         (lptr_t)(void*)b_l1, 16, 0, 0);          \
        __syncthreads();                                                          \
        bf16x8 af[4], bfr[4];                                                     \
        for (int m = 0; m < 4; ++m)                                               \
            af[m] = *reinterpret_cast<const bf16x8*>(As + (wr * 64 + m * 16 + r) * 32 + ko); \
        for (int n = 0; n < 4; ++n)                                               \
            bfr[n] = *reinterpret_cast<const bf16x8*>(Bs + (wc * 64 + n * 16 + r) * 32 + ko); \
        for (int m = 0; m < 4; ++m)                                               \
            for (int n = 0; n < 4; ++n)                                           \
                acc[m][n] = __builtin_amdgcn_mfma_f32_16x16x32_bf16(af[m], bfr[n], acc[m][n], 0, 0, 0); \
        __syncthreads();                                                          \
    }

// ---------------- QKV GEMM -> q/k/v all [B,H,T,64] bf16 (R2 epilogue) ----------------
__global__ __launch_bounds__(256) void k_gemm_qkv(const bf16* __restrict__ A,
                                                  const bf16* __restrict__ Bt,
                                                  const float* __restrict__ bias,
                                                  bf16* __restrict__ qb,
                                                  bf16* __restrict__ kb,
                                                  bf16* __restrict__ vb) {
    const int m0 = blockIdx.x * 128;
    const int n0 = blockIdx.y * 128;
    GEMM_MAINLOOP(A, Bt, m0, n0)
    const int col   = lane & 15;
    const int rbase = (lane >> 4) * 4;
    for (int nn = 0; nn < 4; ++nn) {
        int n = n0 + wc * 64 + nn * 16 + col;
        float bv = bias[n];
        int which = n >> 10;     // 0:q 1:k 2:v
        int c  = n & 1023;
        int h  = c >> 6;
        int dh = c & 63;
        bf16* dst = (which == 0) ? qb : ((which == 1) ? kb : vb);
        for (int mm = 0; mm < 4; ++mm) {
            for (int i = 0; i < 4; ++i) {
                int m = m0 + wr * 64 + mm * 16 + rbase + i;
                int b_ = m >> 11;
                int t  = m & 2047;
                dst[(((b_ * N_HEAD + h) * T_SEQ) + t) * HEAD_DIM + dh] =
                    f2b(acc[mm][nn][i] + bv);
            }
        }
    }
}

// ---------------- proj GEMM: y[4096x1024] @ Wp[1024x1024] + bias -> out f32
__global__ __launch_bounds__(256) void k_gemm_proj(const bf16* __restrict__ A,
                                                   const bf16* __restrict__ Bt,
                                                   const float* __restrict__ bias,
                                                   float* __restrict__ out) {
    const int m0 = blockIdx.x * 128;
    const int n0 = blockIdx.y * 128;
    GEMM_MAINLOOP(A, Bt, m0, n0)
    const int col   = lane & 15;
    const int rbase = (lane >> 4) * 4;
    for (int nn = 0; nn < 4; ++nn) {
        int n = n0 + wc * 64 + nn * 16 + col;
        float bv = bias[n];
        for (int mm = 0; mm < 4; ++mm) {
            for (int i = 0; i < 4; ++i) {
                int m = m0 + wr * 64 + mm * 16 + rbase + i;
                out[(size_t)m * N_EMB + n] = acc[mm][nn][i] + bv;
            }
        }
    }
}

// =====================================================================
// flash attention, swapped-operand 32x32: one wave = 32 q rows.
// S^T = mfma(K,Q): lane owns q-row (lane&31); kpos = (r&3)+8*(r>>2)+4*hi.
// O^T = mfma(V^T, P^T): same lane->q-row mapping, rescale is lane-local.
// No LDS; K/V read direct (L2-resident). Balanced quartets per block.
// =====================================================================
__global__ __launch_bounds__(256) void k_attn(const bf16* __restrict__ qb,
                                              const bf16* __restrict__ kb,
                                              const bf16* __restrict__ vtb,
                                              bf16* __restrict__ yb) {
    const int lane = threadIdx.x & 63;
    const int w    = threadIdx.x >> 6;
    const int bh   = blockIdx.y;
    const int b    = bh >> 4;
    const int h    = bh & 15;
    const int j    = blockIdx.x;  // 0..15
    const int qblk = (w == 0) ? j : (w == 1) ? (31 - j) : (w == 2) ? (32 + j) : (63 - j);
    const int q0   = qblk * 32;

    const bf16* Q  = qb  + (size_t)bh * T_SEQ * HEAD_DIM;
    const bf16* K  = kb  + (size_t)bh * T_SEQ * HEAD_DIM;
    const bf16* Vt = vtb + (size_t)bh * HEAD_DIM * T_SEQ;   // [64][T]

    const int qr = lane & 31;
    const int hi = lane >> 5;

    // Q as B-operand: B[col=qrow][k], k = 8*hi + jj per 16-k fragment
    bf16x8 qf[4];
    #pragma unroll
    for (int f = 0; f < 4; ++f)
        qf[f] = *reinterpret_cast<const bf16x8*>(
            Q + (size_t)(q0 + qr) * HEAD_DIM + f * 16 + hi * 8);

    f32x16 o[2];
    #pragma unroll
    for (int r = 0; r < 16; ++r) { o[0][r] = 0.f; o[1][r] = 0.f; }
    float m_r = -3.0e38f, l_r = 0.f;

    const float cs = 0.125f * 1.4426950408889634f;   // scale * log2(e)
    const int ndiag = q0 / 32;

    for (int kt = 0; kt <= ndiag; ++kt) {
        const int kbase = kt * 32;
        // K as A-operand: A[row=kpos][k]
        bf16x8 kf[4];
        #pragma unroll
        for (int f = 0; f < 4; ++f)
            kf[f] = *reinterpret_cast<const bf16x8*>(
                K + (size_t)(kbase + qr) * HEAD_DIM + f * 16 + hi * 8);
        // V^T as A-operand for PV (independent -> issue early)
        bf16x8 va[2][2];
        #pragma unroll
        for (int dt = 0; dt < 2; ++dt)
            #pragma unroll
            for (int ks = 0; ks < 2; ++ks)
                va[dt][ks] = *reinterpret_cast<const bf16x8*>(
                    Vt + (size_t)(dt * 32 + qr) * T_SEQ + kbase + ks * 16 + hi * 8);

        f32x16 st;
        #pragma unroll
        for (int r = 0; r < 16; ++r) st[r] = 0.f;
        #pragma unroll
        for (int f = 0; f < 4; ++f)
            st = __builtin_amdgcn_mfma_f32_32x32x16_bf16(kf[f], qf[f], st, 0, 0, 0);

        if (kt == ndiag) {   // diagonal tile: causal mask kpos <= qrow
            #pragma unroll
            for (int r = 0; r < 16; ++r) {
                const int kpos = (r & 3) + 8 * (r >> 2) + 4 * hi;
                st[r] = (kpos <= qr) ? st[r] * cs : -3.0e38f;
            }
        } else {
            #pragma unroll
            for (int r = 0; r < 16; ++r) st[r] *= cs;
        }
        // row max: 15 in-lane + 1 cross-half shuffle
        float mt = st[0];
        #pragma unroll
        for (int r = 1; r < 16; ++r) mt = fmaxf(mt, st[r]);
        mt = fmaxf(mt, __shfl_xor(mt, 32, 64));
        const float mn = fmaxf(m_r, mt);
        const float alpha = exp2f(m_r - mn);
        m_r = mn;
        float p[16]; float rs = 0.f;
        #pragma unroll
        for (int r = 0; r < 16; ++r) { p[r] = exp2f(st[r] - mn); rs += p[r]; }
        rs += __shfl_xor(rs, 32, 64);
        l_r = l_r * alpha + rs;
        #pragma unroll
        for (int r = 0; r < 16; ++r) { o[0][r] *= alpha; o[1][r] *= alpha; }
        // P^T -> bf16 B-fragments: pack k-pairs, exchange halves (T12, shfl form)
        u32 c[8], sw[8];
        #pragma unroll
        for (int i = 0; i < 8; ++i) c[i] = pkbf(p[2 * i], p[2 * i + 1]);
        #pragma unroll
        for (int i = 0; i < 8; ++i) sw[i] = __shfl_xor(c[i], 32, 64);
        u32x4 f0, f1;
        f0[0] = hi ? sw[2] : c[0];  f0[1] = hi ? sw[3] : c[1];
        f0[2] = hi ? c[2]  : sw[0]; f0[3] = hi ? c[3]  : sw[1];
        f1[0] = hi ? sw[6] : c[4];  f1[1] = hi ? sw[7] : c[5];
        f1[2] = hi ? c[6]  : sw[4]; f1[3] = hi ? c[7]  : sw[5];
        bf16x8 pb[2];
        pb[0] = __builtin_bit_cast(bf16x8, f0);
        pb[1] = __builtin_bit_cast(bf16x8, f1);
        #pragma unroll
        for (int dt = 0; dt < 2; ++dt)
            #pragma unroll
            for (int ks = 0; ks < 2; ++ks)
                o[dt] = __builtin_amdgcn_mfma_f32_32x32x16_bf16(va[dt][ks], pb[ks], o[dt], 0, 0, 0);
    }
    // epilogue: O^T[d][q] / l  -> y[b][t][h*64+d], packed 8B stores
    const float inv = 1.f / l_r;
    const int t = q0 + qr;
    bf16* yrow = yb + ((size_t)(b * T_SEQ + t)) * N_EMB + h * HEAD_DIM;
    #pragma unroll
    for (int dt = 0; dt < 2; ++dt) {
        #pragma unroll
        for (int rr = 0; rr < 4; ++rr) {
            const int d0 = dt * 32 + 8 * rr + 4 * hi;
            ushort4 u;
            u.x = f2bu(o[dt][4 * rr + 0] * inv);
            u.y = f2bu(o[dt][4 * rr + 1] * inv);
            u.z = f2bu(o[dt][4 * rr + 2] * inv);
            u.w = f2bu(o[dt][4 * rr + 3] * inv);
            *reinterpret_cast<ushort4*>(yrow + d0) = u;
        }
    }
}

extern "C" void kernel_launch(void* const* d_in, const int* in_sizes, int n_in,
                              void* d_out, int out_size, void* d_ws, size_t ws_size,
                              hipStream_t stream) {
    const float* x      = (const float*)d_in[0];
    const float* W_attn = (const float*)d_in[1];
    const float* b_attn = (const float*)d_in[2];
    const float* W_proj = (const float*)d_in[3];
    const float* b_proj = (const float*)d_in[4];
    float* out = (float*)d_out;

    const size_t sz_x   = (size_t)M_TOT * N_EMB;
    const size_t sz_wat = (size_t)N_QKV * N_EMB;
    const size_t sz_wpt = (size_t)N_EMB * N_EMB;
    const size_t sz_hd  = (size_t)BATCH * N_HEAD * T_SEQ * HEAD_DIM;
    const size_t need = (sz_x + sz_wat + sz_wpt + 3 * sz_hd + sz_x) * sizeof(bf16);
    if (ws_size < need) return;

    bf16* xb  = (bf16*)d_ws;       // dead after QKV GEMM -> reused for V^T
    bf16* wat = xb + sz_x;
    bf16* wpt = wat + sz_wat;
    bf16* qb  = wpt + sz_wpt;
    bf16* kbf = qb + sz_hd;
    bf16* vbf = kbf + sz_hd;       // row-major V [B,H,T,64]
    bf16* yb  = vbf + sz_hd;
    bf16* vtb = xb;                // V^T [B,H,64,T] (sz_hd == sz_x)

    k_cast<<<dim3((sz_x / 4 + 255) / 256), 256, 0, stream>>>(x, xb, (int)(sz_x / 4));
    k_transpose<<<dim3(N_EMB / 32, N_QKV / 32), 256, 0, stream>>>(W_attn, wat, N_EMB, N_QKV);
    k_transpose<<<dim3(N_EMB / 32, N_EMB / 32), 256, 0, stream>>>(W_proj, wpt, N_EMB, N_EMB);
    k_gemm_qkv<<<dim3(M_TOT / 128, N_QKV / 128), 256, 0, stream>>>(xb, wat, b_attn, qb, kbf, vbf);
    k_vtrans<<<dim3(T_SEQ / 64, BATCH * N_HEAD), 256, 0, stream>>>(vbf, vtb);
    k_attn<<<dim3(16, BATCH * N_HEAD), 256, 0, stream>>>(qb, kbf, vtb, yb);
    k_gemm_proj<<<dim3(M_TOT / 128, N_EMB / 128), 256, 0, stream>>>(yb, wpt, b_proj, out);
}

// Round 6
// 144.892 us; speedup vs baseline: 2.1611x; 1.0793x over previous
//
#include <hip/hip_runtime.h>
#include <hip/hip_bf16.h>

// ---------------- types ----------------
typedef __bf16 bf16;
typedef __attribute__((ext_vector_type(2))) __bf16 bf16x2;
typedef __attribute__((ext_vector_type(4))) __bf16 bf16x4;
typedef __attribute__((ext_vector_type(8))) __bf16 bf16x8;
typedef __attribute__((ext_vector_type(4))) float f32x4;
typedef __attribute__((ext_vector_type(16))) float f32x16;
typedef unsigned int u32;
typedef __attribute__((ext_vector_type(4))) u32 u32x4;
typedef const __attribute__((address_space(1))) u32* gptr_t;
typedef __attribute__((address_space(3))) u32* lptr_t;

#define N_EMB 1024
#define N_HEAD 16
#define HEAD_DIM 64
#define T_SEQ 2048
#define BATCH 2
#define M_TOT (BATCH * T_SEQ)   // 4096
#define N_QKV (3 * N_EMB)       // 3072
#define KDIM 1024

// round-to-nearest-even f32 -> bf16
__device__ inline unsigned short f2bu(float f) {
    unsigned u = __builtin_bit_cast(unsigned, f);
    return (unsigned short)((u + 0x7fffu + ((u >> 16) & 1u)) >> 16);
}
__device__ inline bf16 f2b(float f) {
    unsigned short s = f2bu(f);
    return __builtin_bit_cast(bf16, s);
}
__device__ inline u32 pkbf(float lo, float hi) {
    bf16x2 t; t[0] = (bf16)lo; t[1] = (bf16)hi;
    return __builtin_bit_cast(u32, t);
}

// ---------------- cast x (f32 -> bf16) ----------------
__global__ __launch_bounds__(256) void k_cast(const float* __restrict__ x,
                                              bf16* __restrict__ xb, int n4) {
    int i = blockIdx.x * 256 + threadIdx.x;
    if (i < n4) {
        float4 v = reinterpret_cast<const float4*>(x)[i];
        ushort4 u;
        u.x = f2bu(v.x); u.y = f2bu(v.y); u.z = f2bu(v.z); u.w = f2bu(v.w);
        reinterpret_cast<ushort4*>(xb)[i] = u;
    }
}

// ---------------- transpose + cast: W [K][N] f32 -> Wt [N][K] bf16 ----------------
__global__ __launch_bounds__(256) void k_transpose(const float* __restrict__ W,
                                                   bf16* __restrict__ Wt,
                                                   int K, int N) {
    __shared__ float tile[32][33];
    int k0 = blockIdx.x * 32;
    int n0 = blockIdx.y * 32;
    int tx = threadIdx.x & 31;
    int ty = threadIdx.x >> 5;
    for (int j = 0; j < 32; j += 8)
        tile[ty + j][tx] = W[(k0 + ty + j) * N + n0 + tx];
    __syncthreads();
    for (int j = 0; j < 32; j += 8)
        Wt[(n0 + ty + j) * (long)K + k0 + tx] = f2b(tile[tx][ty + j]);
}

// ---------------- V transpose: [B,H,T,64] -> [B,H,64,T] via LDS tile ----------------
__global__ __launch_bounds__(256) void k_vtrans(const bf16* __restrict__ v,
                                                bf16* __restrict__ vt) {
    __shared__ bf16 tile[64 * 76];
    const int bh = blockIdx.y;
    const int t0 = blockIdx.x * 64;
    const bf16* src = v + (size_t)bh * T_SEQ * HEAD_DIM;
    bf16* dst = vt + (size_t)bh * HEAD_DIM * T_SEQ;
    const int tid = threadIdx.x;
    #pragma unroll
    for (int it = 0; it < 2; ++it) {
        const int row = (tid >> 3) + it * 32;
        const int col = (tid & 7) * 8;
        bf16x8 val = *reinterpret_cast<const bf16x8*>(src + (size_t)(t0 + row) * HEAD_DIM + col);
        bf16x4 lo;  lo[0] = val[0]; lo[1] = val[1]; lo[2] = val[2]; lo[3] = val[3];
        bf16x4 hiv; hiv[0] = val[4]; hiv[1] = val[5]; hiv[2] = val[6]; hiv[3] = val[7];
        *reinterpret_cast<bf16x4*>(&tile[row * 76 + col]) = lo;
        *reinterpret_cast<bf16x4*>(&tile[row * 76 + col + 4]) = hiv;
    }
    __syncthreads();
    #pragma unroll
    for (int it = 0; it < 2; ++it) {
        const int d  = (tid >> 3) + it * 32;
        const int tt = (tid & 7) * 8;
        bf16x8 val;
        #pragma unroll
        for (int q = 0; q < 8; ++q)
            val[q] = tile[(tt + q) * 76 + d];
        *reinterpret_cast<bf16x8*>(dst + (size_t)d * T_SEQ + t0 + tt) = val;
    }
}

// =====================================================================
// 128x128 GEMM main loop (m97 structure) — used by QKV
// =====================================================================
#define GEMM_MAINLOOP(A_, Bt_, m0_, n0_)                                          \
    __shared__ __align__(16) bf16 As[128 * 32];                                   \
    __shared__ __align__(16) bf16 Bs[128 * 32];                                   \
    const int lane = threadIdx.x & 63;                                            \
    const int w    = threadIdx.x >> 6;                                            \
    const int wr   = w >> 1;                                                      \
    const int wc   = w & 1;                                                       \
    const int r    = lane & 15;                                                   \
    const int ko   = (lane >> 4) * 8;                                             \
    const int srow = w * 32 + (lane >> 2);                                        \
    const int sk   = (lane & 3) * 8;                                              \
    const bf16* a_g0 = A_ + (size_t)(m0_ + srow) * KDIM + sk;                     \
    const bf16* a_g1 = a_g0 + 16 * KDIM;                                          \
    const bf16* b_g0 = Bt_ + (size_t)(n0_ + srow) * KDIM + sk;                    \
    const bf16* b_g1 = b_g0 + 16 * KDIM;                                          \
    bf16* a_l0 = As + (w * 2) * 512;                                              \
    bf16* a_l1 = As + (w * 2 + 1) * 512;                                          \
    bf16* b_l0 = Bs + (w * 2) * 512;                                              \
    bf16* b_l1 = Bs + (w * 2 + 1) * 512;                                          \
    f32x4 acc[4][4];                                                              \
    for (int i = 0; i < 4; ++i)                                                   \
        for (int j = 0; j < 4; ++j) acc[i][j] = (f32x4){0.f, 0.f, 0.f, 0.f};      \
    for (int k0 = 0; k0 < KDIM; k0 += 32) {                                       \
        __builtin_amdgcn_global_load_lds((gptr_t)(const void*)(a_g0 + k0),        \
                                         (lptr_t)(void*)a_l0, 16, 0, 0);          \
        __builtin_amdgcn_global_load_lds((gptr_t)(const void*)(a_g1 + k0),        \
                                         (lptr_t)(void*)a_l1, 16, 0, 0);          \
        __builtin_amdgcn_global_load_lds((gptr_t)(const void*)(b_g0 + k0),        \
                                         (lptr_t)(void*)b_l0, 16, 0, 0);          \
        __builtin_amdgcn_global_load_lds((gptr_t)(const void*)(b_g1 + k0),        \
                                         (lptr_t)(void*)b_l1, 16, 0, 0);          \
        __syncthreads();                                                          \
        bf16x8 af[4], bfr[4];                                                     \
        for (int m = 0; m < 4; ++m)                                               \
            af[m] = *reinterpret_cast<const bf16x8*>(As + (wr * 64 + m * 16 + r) * 32 + ko); \
        for (int n = 0; n < 4; ++n)                                               \
            bfr[n] = *reinterpret_cast<const bf16x8*>(Bs + (wc * 64 + n * 16 + r) * 32 + ko); \
        for (int m = 0; m < 4; ++m)                                               \
            for (int n = 0; n < 4; ++n)                                           \
                acc[m][n] = __builtin_amdgcn_mfma_f32_16x16x32_bf16(af[m], bfr[n], acc[m][n], 0, 0, 0); \
        __syncthreads();                                                          \
    }

// =====================================================================
// 64x128 GEMM main loop — used by proj (512 blocks -> 2 blocks/CU)
// =====================================================================
#define GEMM_MAINLOOP_64(A_, Bt_, m0_, n0_)                                       \
    __shared__ __align__(16) bf16 As[64 * 32];                                    \
    __shared__ __align__(16) bf16 Bs[128 * 32];                                   \
    const int lane = threadIdx.x & 63;                                            \
    const int w    = threadIdx.x >> 6;                                            \
    const int wr   = w >> 1;                                                      \
    const int wc   = w & 1;                                                       \
    const int r    = lane & 15;                                                   \
    const int ko   = (lane >> 4) * 8;                                             \
    const int srow = w * 16 + (lane >> 2);                                        \
    const int sk   = (lane & 3) * 8;                                              \
    const bf16* a_g0 = A_ + (size_t)(m0_ + srow) * KDIM + sk;                     \
    const bf16* b_g0 = Bt_ + (size_t)(n0_ + srow) * KDIM + sk;                    \
    const bf16* b_g1 = b_g0 + 64 * KDIM;                                          \
    bf16* a_l0 = As + w * 512;                                                    \
    bf16* b_l0 = Bs + w * 512;                                                    \
    bf16* b_l1 = Bs + 64 * 32 + w * 512;                                          \
    f32x4 acc[2][4];                                                              \
    for (int i = 0; i < 2; ++i)                                                   \
        for (int j = 0; j < 4; ++j) acc[i][j] = (f32x4){0.f, 0.f, 0.f, 0.f};      \
    for (int k0 = 0; k0 < KDIM; k0 += 32) {                                       \
        __builtin_amdgcn_global_load_lds((gptr_t)(const void*)(a_g0 + k0),        \
                                         (lptr_t)(void*)a_l0, 16, 0, 0);          \
        __builtin_amdgcn_global_load_lds((gptr_t)(const void*)(b_g0 + k0),        \
                                         (lptr_t)(void*)b_l0, 16, 0, 0);          \
        __builtin_amdgcn_global_load_lds((gptr_t)(const void*)(b_g1 + k0),        \
                                         (lptr_t)(void*)b_l1, 16, 0, 0);          \
        __syncthreads();                                                          \
        bf16x8 af[2], bfr[4];                                                     \
        for (int m = 0; m < 2; ++m)                                               \
            af[m] = *reinterpret_cast<const bf16x8*>(As + (wr * 32 + m * 16 + r) * 32 + ko); \
        for (int n = 0; n < 4; ++n)                                               \
            bfr[n] = *reinterpret_cast<const bf16x8*>(Bs + (wc * 64 + n * 16 + r) * 32 + ko); \
        for (int m = 0; m < 2; ++m)                                               \
            for (int n = 0; n < 4; ++n)                                           \
                acc[m][n] = __builtin_amdgcn_mfma_f32_16x16x32_bf16(af[m], bfr[n], acc[m][n], 0, 0, 0); \
        __syncthreads();                                                          \
    }

// ---------------- QKV GEMM -> q/k/v [B,H,T,64] bf16 ----------------
__global__ __launch_bounds__(256) void k_gemm_qkv(const bf16* __restrict__ A,
                                                  const bf16* __restrict__ Bt,
                                                  const float* __restrict__ bias,
                                                  bf16* __restrict__ qb,
                                                  bf16* __restrict__ kb,
                                                  bf16* __restrict__ vb) {
    const int m0 = blockIdx.x * 128;
    const int n0 = blockIdx.y * 128;
    GEMM_MAINLOOP(A, Bt, m0, n0)
    const int col   = lane & 15;
    const int rbase = (lane >> 4) * 4;
    for (int nn = 0; nn < 4; ++nn) {
        int n = n0 + wc * 64 + nn * 16 + col;
        float bv = bias[n];
        int which = n >> 10;
        int c  = n & 1023;
        int h  = c >> 6;
        int dh = c & 63;
        bf16* dst = (which == 0) ? qb : ((which == 1) ? kb : vb);
        for (int mm = 0; mm < 4; ++mm) {
            for (int i = 0; i < 4; ++i) {
                int m = m0 + wr * 64 + mm * 16 + rbase + i;
                int b_ = m >> 11;
                int t  = m & 2047;
                dst[(((b_ * N_HEAD + h) * T_SEQ) + t) * HEAD_DIM + dh] =
                    f2b(acc[mm][nn][i] + bv);
            }
        }
    }
}

// ---------------- proj GEMM (64x128 tiles) ----------------
__global__ __launch_bounds__(256) void k_gemm_proj(const bf16* __restrict__ A,
                                                   const bf16* __restrict__ Bt,
                                                   const float* __restrict__ bias,
                                                   float* __restrict__ out) {
    const int m0 = blockIdx.x * 64;
    const int n0 = blockIdx.y * 128;
    GEMM_MAINLOOP_64(A, Bt, m0, n0)
    const int col   = lane & 15;
    const int rbase = (lane >> 4) * 4;
    for (int nn = 0; nn < 4; ++nn) {
        int n = n0 + wc * 64 + nn * 16 + col;
        float bv = bias[n];
        for (int mm = 0; mm < 2; ++mm) {
            for (int i = 0; i < 4; ++i) {
                int m = m0 + wr * 32 + mm * 16 + rbase + i;
                out[(size_t)m * N_EMB + n] = acc[mm][nn][i] + bv;
            }
        }
    }
}

// =====================================================================
// flash attention helpers (swapped-operand 32x32, lane owns q-row)
// =====================================================================
__device__ __forceinline__ void pv_group(const float* p, int hi,
                                         const bf16x8 (&va)[2][2], f32x16 (&o)[2]) {
    u32 c[8], sw[8];
    #pragma unroll
    for (int i = 0; i < 8; ++i) c[i] = pkbf(p[2 * i], p[2 * i + 1]);
    #pragma unroll
    for (int i = 0; i < 8; ++i) sw[i] = __shfl_xor(c[i], 32, 64);
    u32x4 f0, f1;
    f0[0] = hi ? sw[2] : c[0];  f0[1] = hi ? sw[3] : c[1];
    f0[2] = hi ? c[2]  : sw[0]; f0[3] = hi ? c[3]  : sw[1];
    f1[0] = hi ? sw[6] : c[4];  f1[1] = hi ? sw[7] : c[5];
    f1[2] = hi ? c[6]  : sw[4]; f1[3] = hi ? c[7]  : sw[5];
    bf16x8 pb0 = __builtin_bit_cast(bf16x8, f0);
    bf16x8 pb1 = __builtin_bit_cast(bf16x8, f1);
    __builtin_amdgcn_s_setprio(1);
    #pragma unroll
    for (int dt = 0; dt < 2; ++dt) {
        o[dt] = __builtin_amdgcn_mfma_f32_32x32x16_bf16(va[dt][0], pb0, o[dt], 0, 0, 0);
        o[dt] = __builtin_amdgcn_mfma_f32_32x32x16_bf16(va[dt][1], pb1, o[dt], 0, 0, 0);
    }
    __builtin_amdgcn_s_setprio(0);
}

// 64-wide KV tile; DIAG_HI: second 32-group is the diagonal (mask kpos<=qr)
template<bool DIAG_HI>
__device__ __forceinline__ void attn_tile64(
    const bf16* __restrict__ K, const bf16* __restrict__ Vt, int kbase,
    int qr, int hi, const bf16x8 (&qf)[4], float cs,
    float& m_r, float& l_r, f32x16 (&o)[2]) {
    bf16x8 kf0[4], kf1[4];
    #pragma unroll
    for (int f = 0; f < 4; ++f) {
        kf0[f] = *reinterpret_cast<const bf16x8*>(
            K + (size_t)(kbase + qr) * HEAD_DIM + f * 16 + hi * 8);
        kf1[f] = *reinterpret_cast<const bf16x8*>(
            K + (size_t)(kbase + 32 + qr) * HEAD_DIM + f * 16 + hi * 8);
    }
    bf16x8 va0[2][2], va1[2][2];
    #pragma unroll
    for (int dt = 0; dt < 2; ++dt)
        #pragma unroll
        for (int ks = 0; ks < 2; ++ks) {
            va0[dt][ks] = *reinterpret_cast<const bf16x8*>(
                Vt + (size_t)(dt * 32 + qr) * T_SEQ + kbase + ks * 16 + hi * 8);
            va1[dt][ks] = *reinterpret_cast<const bf16x8*>(
                Vt + (size_t)(dt * 32 + qr) * T_SEQ + kbase + 32 + ks * 16 + hi * 8);
        }
    f32x16 st0, st1;
    #pragma unroll
    for (int r = 0; r < 16; ++r) { st0[r] = 0.f; st1[r] = 0.f; }
    __builtin_amdgcn_s_setprio(1);
    #pragma unroll
    for (int f = 0; f < 4; ++f)
        st0 = __builtin_amdgcn_mfma_f32_32x32x16_bf16(kf0[f], qf[f], st0, 0, 0, 0);
    #pragma unroll
    for (int f = 0; f < 4; ++f)
        st1 = __builtin_amdgcn_mfma_f32_32x32x16_bf16(kf1[f], qf[f], st1, 0, 0, 0);
    __builtin_amdgcn_s_setprio(0);
    #pragma unroll
    for (int r = 0; r < 16; ++r) st0[r] *= cs;
    if (DIAG_HI) {
        const int kp4 = 4 * hi;
        #pragma unroll
        for (int r = 0; r < 16; ++r) {
            const int kpos = (r & 3) + 8 * (r >> 2) + kp4;
            st1[r] = (kpos <= qr) ? st1[r] * cs : -3.0e38f;
        }
    } else {
        #pragma unroll
        for (int r = 0; r < 16; ++r) st1[r] *= cs;
    }
    float mt = st0[0];
    #pragma unroll
    for (int r = 1; r < 16; ++r) mt = fmaxf(mt, st0[r]);
    #pragma unroll
    for (int r = 0; r < 16; ++r) mt = fmaxf(mt, st1[r]);
    mt = fmaxf(mt, __shfl_xor(mt, 32, 64));
    if (!__all(mt <= m_r + 8.f)) {       // defer-max (T13), log2 domain
        const float mn = fmaxf(m_r, mt);
        const float alpha = exp2f(m_r - mn);
        m_r = mn;
        l_r *= alpha;
        #pragma unroll
        for (int r = 0; r < 16; ++r) { o[0][r] *= alpha; o[1][r] *= alpha; }
    }
    float p0[16], p1[16];
    float rs = 0.f;
    #pragma unroll
    for (int r = 0; r < 16; ++r) { p0[r] = exp2f(st0[r] - m_r); rs += p0[r]; }
    #pragma unroll
    for (int r = 0; r < 16; ++r) { p1[r] = exp2f(st1[r] - m_r); rs += p1[r]; }
    rs += __shfl_xor(rs, 32, 64);
    l_r += rs;
    pv_group(p0, hi, va0, o);
    pv_group(p1, hi, va1, o);
}

// 32-wide diagonal tile (masked)
__device__ __forceinline__ void attn_tile32_diag(
    const bf16* __restrict__ K, const bf16* __restrict__ Vt, int kbase,
    int qr, int hi, const bf16x8 (&qf)[4], float cs,
    float& m_r, float& l_r, f32x16 (&o)[2]) {
    bf16x8 kf[4];
    #pragma unroll
    for (int f = 0; f < 4; ++f)
        kf[f] = *reinterpret_cast<const bf16x8*>(
            K + (size_t)(kbase + qr) * HEAD_DIM + f * 16 + hi * 8);
    bf16x8 va[2][2];
    #pragma unroll
    for (int dt = 0; dt < 2; ++dt)
        #pragma unroll
        for (int ks = 0; ks < 2; ++ks)
            va[dt][ks] = *reinterpret_cast<const bf16x8*>(
                Vt + (size_t)(dt * 32 + qr) * T_SEQ + kbase + ks * 16 + hi * 8);
    f32x16 st;
    #pragma unroll
    for (int r = 0; r < 16; ++r) st[r] = 0.f;
    __builtin_amdgcn_s_setprio(1);
    #pragma unroll
    for (int f = 0; f < 4; ++f)
        st = __builtin_amdgcn_mfma_f32_32x32x16_bf16(kf[f], qf[f], st, 0, 0, 0);
    __builtin_amdgcn_s_setprio(0);
    const int kp4 = 4 * hi;
    #pragma unroll
    for (int r = 0; r < 16; ++r) {
        const int kpos = (r & 3) + 8 * (r >> 2) + kp4;
        st[r] = (kpos <= qr) ? st[r] * cs : -3.0e38f;
    }
    float mt = st[0];
    #pragma unroll
    for (int r = 1; r < 16; ++r) mt = fmaxf(mt, st[r]);
    mt = fmaxf(mt, __shfl_xor(mt, 32, 64));
    if (!__all(mt <= m_r + 8.f)) {
        const float mn = fmaxf(m_r, mt);
        const float alpha = exp2f(m_r - mn);
        m_r = mn;
        l_r *= alpha;
        #pragma unroll
        for (int r = 0; r < 16; ++r) { o[0][r] *= alpha; o[1][r] *= alpha; }
    }
    float p[16];
    float rs = 0.f;
    #pragma unroll
    for (int r = 0; r < 16; ++r) { p[r] = exp2f(st[r] - m_r); rs += p[r]; }
    rs += __shfl_xor(rs, 32, 64);
    l_r += rs;
    pv_group(p, hi, va, o);
}

// =====================================================================
// flash attention: one wave = 32 q rows, KVBLK=64, defer-max.
// grid (bh=32, j=16): linear block id % 8 == bh % 8 -> head pinned to XCD,
// K+V^T per XCD = 4 heads x 512KB = 2MB (L2-fits).
// =====================================================================
__global__ __launch_bounds__(256) void k_attn(const bf16* __restrict__ qb,
                                              const bf16* __restrict__ kb,
                                              const bf16* __restrict__ vtb,
                                              bf16* __restrict__ yb) {
    const int lane = threadIdx.x & 63;
    const int w    = threadIdx.x >> 6;
    const int bh   = blockIdx.x;   // 0..31  (XCD = bh % 8)
    const int j    = blockIdx.y;   // 0..15
    const int b    = bh >> 4;
    const int h    = bh & 15;
    const int qblk = (w == 0) ? j : (w == 1) ? (31 - j) : (w == 2) ? (32 + j) : (63 - j);
    const int q0   = qblk * 32;

    const bf16* Q  = qb  + (size_t)bh * T_SEQ * HEAD_DIM;
    const bf16* K  = kb  + (size_t)bh * T_SEQ * HEAD_DIM;
    const bf16* Vt = vtb + (size_t)bh * HEAD_DIM * T_SEQ;

    const int qr = lane & 31;
    const int hi = lane >> 5;

    bf16x8 qf[4];
    #pragma unroll
    for (int f = 0; f < 4; ++f)
        qf[f] = *reinterpret_cast<const bf16x8*>(
            Q + (size_t)(q0 + qr) * HEAD_DIM + f * 16 + hi * 8);

    f32x16 o[2];
    #pragma unroll
    for (int r = 0; r < 16; ++r) { o[0][r] = 0.f; o[1][r] = 0.f; }
    float m_r = -3.0e38f, l_r = 0.f;

    const float cs = 0.125f * 1.4426950408889634f;   // scale * log2(e)

    const int nfull = q0 >> 6;   // full 64-wide tiles strictly below diagonal
    for (int kt = 0; kt < nfull; ++kt)
        attn_tile64<false>(K, Vt, kt * 64, qr, hi, qf, cs, m_r, l_r, o);
    if (qblk & 1)
        attn_tile64<true>(K, Vt, q0 - 32, qr, hi, qf, cs, m_r, l_r, o);
    else
        attn_tile32_diag(K, Vt, q0, qr, hi, qf, cs, m_r, l_r, o);

    // epilogue
    const float inv = 1.f / l_r;
    const int t = q0 + qr;
    bf16* yrow = yb + ((size_t)(b * T_SEQ + t)) * N_EMB + h * HEAD_DIM;
    #pragma unroll
    for (int dt = 0; dt < 2; ++dt) {
        #pragma unroll
        for (int rr = 0; rr < 4; ++rr) {
            const int d0 = dt * 32 + 8 * rr + 4 * hi;
            ushort4 u;
            u.x = f2bu(o[dt][4 * rr + 0] * inv);
            u.y = f2bu(o[dt][4 * rr + 1] * inv);
            u.z = f2bu(o[dt][4 * rr + 2] * inv);
            u.w = f2bu(o[dt][4 * rr + 3] * inv);
            *reinterpret_cast<ushort4*>(yrow + d0) = u;
        }
    }
}

extern "C" void kernel_launch(void* const* d_in, const int* in_sizes, int n_in,
                              void* d_out, int out_size, void* d_ws, size_t ws_size,
                              hipStream_t stream) {
    const float* x      = (const float*)d_in[0];
    const float* W_attn = (const float*)d_in[1];
    const float* b_attn = (const float*)d_in[2];
    const float* W_proj = (const float*)d_in[3];
    const float* b_proj = (const float*)d_in[4];
    float* out = (float*)d_out;

    const size_t sz_x   = (size_t)M_TOT * N_EMB;
    const size_t sz_wat = (size_t)N_QKV * N_EMB;
    const size_t sz_wpt = (size_t)N_EMB * N_EMB;
    const size_t sz_hd  = (size_t)BATCH * N_HEAD * T_SEQ * HEAD_DIM;
    const size_t need = (sz_x + sz_wat + sz_wpt + 3 * sz_hd + sz_x) * sizeof(bf16);
    if (ws_size < need) return;

    bf16* xb  = (bf16*)d_ws;       // dead after QKV GEMM -> reused for V^T
    bf16* wat = xb + sz_x;
    bf16* wpt = wat + sz_wat;
    bf16* qb  = wpt + sz_wpt;
    bf16* kbf = qb + sz_hd;
    bf16* vbf = kbf + sz_hd;
    bf16* yb  = vbf + sz_hd;
    bf16* vtb = xb;                // V^T [B,H,64,T]

    k_cast<<<dim3((sz_x / 4 + 255) / 256), 256, 0, stream>>>(x, xb, (int)(sz_x / 4));
    k_transpose<<<dim3(N_EMB / 32, N_QKV / 32), 256, 0, stream>>>(W_attn, wat, N_EMB, N_QKV);
    k_transpose<<<dim3(N_EMB / 32, N_EMB / 32), 256, 0, stream>>>(W_proj, wpt, N_EMB, N_EMB);
    k_gemm_qkv<<<dim3(M_TOT / 128, N_QKV / 128), 256, 0, stream>>>(xb, wat, b_attn, qb, kbf, vbf);
    k_vtrans<<<dim3(T_SEQ / 64, BATCH * N_HEAD), 256, 0, stream>>>(vbf, vtb);
    k_attn<<<dim3(BATCH * N_HEAD, 16), 256, 0, stream>>>(qb, kbf, vtb, yb);
    k_gemm_proj<<<dim3(M_TOT / 64, N_EMB / 128), 256, 0, stream>>>(yb, wpt, b_proj, out);
}